// Round 1
// baseline (118.168 us; speedup 1.0000x reference)
//
#include <hip/hip_runtime.h>

// WanRotaryPosEmbedS2VStyle: build (cos, sin) RoPE grids.
// Output 0: freqs_cos (1, F*height*width, 1, 128) f32
// Output 1: freqs_sin (same shape), concatenated flat after cos in d_out.
//
// Per element (f, y, x, d):
//   d <  44        -> t_tab[pos_t[f]][d]          (T_DIM = 44)
//   44 <= d < 86   -> h_tab[y][d-44]              (H_DIM = 42)
//   86 <= d < 128  -> w_tab[x][d-86]              (W_DIM = 42)
// pos_t[f] = f if f < num_video_frames else 30 (FIXED_REF), with p_t = 1.

#define RP_T_DIM 44
#define RP_H_DIM 42
#define RP_W_DIM 42
#define RP_HEAD_DIM 128
#define RP_FIXED_REF 30

__global__ __launch_bounds__(256) void wan_rope_kernel(
    const float* __restrict__ t_cos, const float* __restrict__ h_cos,
    const float* __restrict__ w_cos, const float* __restrict__ t_sin,
    const float* __restrict__ h_sin, const float* __restrict__ w_sin,
    const int* __restrict__ nvf_ptr,
    float* __restrict__ out,
    int height, int width, long long sin_offset)
{
    const int rows_per_frame = height * width;            // 3600
    const int quads_per_frame = rows_per_frame * (RP_HEAD_DIM / 4); // 3600*32
    const int tid = blockIdx.x * blockDim.x + threadIdx.x;
    if (tid >= quads_per_frame) return;

    const int f   = blockIdx.y;
    const int row = tid >> 5;         // 0 .. rows_per_frame-1
    const int d0  = (tid & 31) << 2;  // 0,4,...,124
    const int y   = row / width;
    const int x   = row - y * width;

    const int video_pp = nvf_ptr[0];  // p_t == 1
    const int pos = (f < video_pp) ? f : RP_FIXED_REF;

    float cv[4], sv[4];
#pragma unroll
    for (int j = 0; j < 4; ++j) {
        const int d = d0 + j;
        float cc, ss;
        if (d < RP_T_DIM) {
            cc = t_cos[pos * RP_T_DIM + d];
            ss = t_sin[pos * RP_T_DIM + d];
        } else if (d < RP_T_DIM + RP_H_DIM) {
            const int dd = d - RP_T_DIM;
            cc = h_cos[y * RP_H_DIM + dd];
            ss = h_sin[y * RP_H_DIM + dd];
        } else {
            const int dd = d - RP_T_DIM - RP_H_DIM;
            cc = w_cos[x * RP_W_DIM + dd];
            ss = w_sin[x * RP_W_DIM + dd];
        }
        cv[j] = cc;
        sv[j] = ss;
    }

    const long long base =
        ((long long)f * rows_per_frame + row) * RP_HEAD_DIM + d0;
    *(float4*)(out + base) = make_float4(cv[0], cv[1], cv[2], cv[3]);
    *(float4*)(out + sin_offset + base) = make_float4(sv[0], sv[1], sv[2], sv[3]);
}

extern "C" void kernel_launch(void* const* d_in, const int* in_sizes, int n_in,
                              void* d_out, int out_size, void* d_ws, size_t ws_size,
                              hipStream_t stream) {
    // Input order (setup_inputs dict): hidden_states, freq_t_cos, freq_h_cos,
    // freq_w_cos, freq_t_sin, freq_h_sin, freq_w_sin, num_video_frames,
    // num_ref_frames.
    const float* t_cos = (const float*)d_in[1];
    const float* h_cos = (const float*)d_in[2];
    const float* w_cos = (const float*)d_in[3];
    const float* t_sin = (const float*)d_in[4];
    const float* h_sin = (const float*)d_in[5];
    const float* w_sin = (const float*)d_in[6];
    const int*   nvf   = (const int*)d_in[7];
    float* out = (float*)d_out;

    // hidden_states is (1, 16, 22, 120, 120), patch (1,2,2) -> 60x60 grid.
    const int height = 60, width = 60;

    // out_size = 2 * F * height*width * HEAD_DIM  ->  derive F (no D2H sync).
    const long long per_out = (long long)out_size / 2;
    const int F = (int)(per_out / ((long long)height * width * RP_HEAD_DIM));

    const int quads_per_frame = height * width * (RP_HEAD_DIM / 4);
    dim3 block(256);
    dim3 grid((quads_per_frame + 255) / 256, F);
    wan_rope_kernel<<<grid, block, 0, stream>>>(
        t_cos, h_cos, w_cos, t_sin, h_sin, w_sin, nvf,
        out, height, width, per_out);
}

// Round 2
// 111.426 us; speedup vs baseline: 1.0605x; 1.0605x over previous
//
#include <hip/hip_runtime.h>

// WanRotaryPosEmbedS2VStyle: build (cos, sin) RoPE grids.
// out[0..per_out)       = freqs_cos (1, F*60*60, 1, 128) f32
// out[per_out..2*per_out)= freqs_sin
//
// Per element (f, y, x, d):
//   d <  44        -> t_tab[pos][d],   pos = f < num_video_frames ? f : 30
//   44 <= d < 86   -> h_tab[y][d-44]
//   86 <= d < 128  -> w_tab[x][d-86]
//
// Strategy: one block per (f, y). Stage t||h (86 floats) and the padded
// w-table (60 rows x stride 44; row head = h[40],h[41] so the straddling
// quad q=21 [d 84..87] is one aligned 16B read) into LDS, then stream out
// whole rows with branchless ds_read_b128 + coalesced float4 stores.

#define RP_T_DIM 44
#define RP_H_DIM 42
#define RP_W_DIM 42
#define RP_HEAD 128
#define RP_GH 60
#define RP_GW 60
#define RP_FIXED_REF 30
#define RP_TH 86          // t||h head length
#define RP_TH_PAD 88      // padded (16B-mult) head region
#define RP_WROW 44        // padded w row: [h40, h41, w0..w41]
#define RP_LDS_FLOATS (RP_TH_PAD + RP_GW * RP_WROW)   // 88 + 2640 = 2728

#define RP_BLOCK 320      // 5 waves; 1920 quads / 320 = 6 iters exactly

__global__ __launch_bounds__(RP_BLOCK) void wan_rope_kernel(
    const float* __restrict__ t_cos, const float* __restrict__ h_cos,
    const float* __restrict__ w_cos, const float* __restrict__ t_sin,
    const float* __restrict__ h_sin, const float* __restrict__ w_sin,
    const int* __restrict__ nvf_ptr,
    float* __restrict__ out, long long sin_offset)
{
    __shared__ __align__(16) float lds_c[RP_LDS_FLOATS];
    __shared__ __align__(16) float lds_s[RP_LDS_FLOATS];

    const int tid = threadIdx.x;
    const int y = blockIdx.x;     // 0..59
    const int f = blockIdx.y;     // 0..F-1

    const int vpp = nvf_ptr[0];   // num_video_frames (p_t == 1)
    const int pos = (f < vpp) ? f : RP_FIXED_REF;

    // ---- stage t||h head: floats [0,86) = t[pos][0..43] || h[y][0..41]
    if (tid < RP_T_DIM) {
        lds_c[tid] = t_cos[pos * RP_T_DIM + tid];
        lds_s[tid] = t_sin[pos * RP_T_DIM + tid];
    } else if (tid < RP_TH) {
        const int j = tid - RP_T_DIM;
        lds_c[tid] = h_cos[y * RP_H_DIM + j];
        lds_s[tid] = h_sin[y * RP_H_DIM + j];
    }

    // ---- replicate h[40],h[41] into each padded w-row head (120 slots)
    for (int i = tid; i < 2 * RP_GW; i += RP_BLOCK) {
        const int x = i >> 1, j = i & 1;
        lds_c[RP_TH_PAD + x * RP_WROW + j] = h_cos[y * RP_H_DIM + 40 + j];
        lds_s[RP_TH_PAD + x * RP_WROW + j] = h_sin[y * RP_H_DIM + 40 + j];
    }

    // ---- stage w table body: w[x][j] -> wrow[x][2+j]  (2520 contiguous reads)
    for (int sIdx = tid; sIdx < RP_GW * RP_W_DIM; sIdx += RP_BLOCK) {
        const int x = sIdx / RP_W_DIM;
        const int j = sIdx - x * RP_W_DIM;
        lds_c[RP_TH_PAD + x * RP_WROW + 2 + j] = w_cos[sIdx];
        lds_s[RP_TH_PAD + x * RP_WROW + 2 + j] = w_sin[sIdx];
    }

    __syncthreads();

    // ---- main loop: 1920 output quads (60 x's * 32 quads), cos+sin each
    const long long rowbase = (long long)f * (RP_GH * RP_GW) + y * RP_GW;
#pragma unroll
    for (int it = 0; it < 6; ++it) {
        const int flat = it * RP_BLOCK + tid;   // [0, 1920)
        const int x = flat >> 5;                // 0..59
        const int q = flat & 31;                // quad index: d = 4q..4q+3
        // q in [0,21): t||h head at 4q (16B aligned).
        // q in [21,32): padded w row at x*44 + 4*(q-21) (16B aligned);
        //   q==21 reads {h40,h41,w0,w1} covering the d=84..87 straddle.
        const int lidx = (q < 21) ? (q << 2)
                                  : (RP_TH_PAD + x * RP_WROW + ((q - 21) << 2));
        const float4 c = *(const float4*)(lds_c + lidx);
        const float4 s = *(const float4*)(lds_s + lidx);
        const long long base = (rowbase + x) * RP_HEAD + (q << 2);
        *(float4*)(out + base) = c;
        *(float4*)(out + sin_offset + base) = s;
    }
}

extern "C" void kernel_launch(void* const* d_in, const int* in_sizes, int n_in,
                              void* d_out, int out_size, void* d_ws, size_t ws_size,
                              hipStream_t stream) {
    // Input order: hidden_states, freq_t_cos, freq_h_cos, freq_w_cos,
    // freq_t_sin, freq_h_sin, freq_w_sin, num_video_frames, num_ref_frames.
    const float* t_cos = (const float*)d_in[1];
    const float* h_cos = (const float*)d_in[2];
    const float* w_cos = (const float*)d_in[3];
    const float* t_sin = (const float*)d_in[4];
    const float* h_sin = (const float*)d_in[5];
    const float* w_sin = (const float*)d_in[6];
    const int*   nvf   = (const int*)d_in[7];
    float* out = (float*)d_out;

    // hidden_states (1,16,22,120,120), patch (1,2,2) -> 60x60 grid.
    // out_size = 2 * F * 3600 * 128 -> derive F (no D2H sync).
    const long long per_out = (long long)out_size / 2;
    const int F = (int)(per_out / ((long long)RP_GH * RP_GW * RP_HEAD));

    dim3 block(RP_BLOCK);
    dim3 grid(RP_GH, F);   // (y, f)
    wan_rope_kernel<<<grid, block, 0, stream>>>(
        t_cos, h_cos, w_cos, t_sin, h_sin, w_sin, nvf, out, per_out);
}